// Round 15
// baseline (410.562 us; speedup 1.0000x reference)
//
#include <hip/hip_runtime.h>
#include <cstdint>
#include <cstddef>

// ---------------------------------------------------------------------------
// SimpleGNN: 2x GCNConv(128->128) + ReLU, global mean pool (64 graphs),
// MLP head 128->128->128 + ReLU, L2 row-normalize.
//
// R15 changes vs R14 (221us; aggr 2x49us structural; rest=123us dominated by
// CSR-chain LDS-atomic serialization + pool/launch overhead):
//  - k_bincount/k_bin/k_fill2: WAVE-PRIVATE LDS histograms + wave-private
//    placement cursors (sub-chunk bases from merged prefix) -> ~4x less
//    same-bank atomic serialization. Same bytes moved.
//  - k_pool DELETED: k_head pools directly (binary search of sorted batch
//    for the graph's node range; f32 accumulate; count = range length).
//  - aggr/gemm unchanged (pinned at floors).
// ---------------------------------------------------------------------------

using short8 = __attribute__((ext_vector_type(8))) short;   // 8 bf16 (4 VGPRs)
using f32x4v = __attribute__((ext_vector_type(4))) float;   // 4 fp32

// ---------------- bf16 helpers ----------------

static __device__ __forceinline__ unsigned f2bf_rne(float f) {
    unsigned u = __float_as_uint(f);
    return (u + 0x7FFFu + ((u >> 16) & 1u)) >> 16;   // round-nearest-even
}
static __device__ __forceinline__ unsigned pack_bf2(float lo, float hi) {
    return f2bf_rne(lo) | (f2bf_rne(hi) << 16);
}
static __device__ __forceinline__ float bf_lo(unsigned v) {
    return __uint_as_float(v << 16);
}
static __device__ __forceinline__ float bf_hi(unsigned v) {
    return __uint_as_float(v & 0xFFFF0000u);
}

// ---------------- pass 0: bucket counts (bucket = 256 consecutive dst) ----
// wave-private histograms -> 4x less LDS-atomic contention

__global__ void k_bincount(const int* __restrict__ dst, int* __restrict__ bcnt,
                           int E, int NB) {
    __shared__ int h4[4][256];
    int t = threadIdx.x;
    int w = t >> 6;
    ((int*)h4)[t]       = 0;
    ((int*)h4)[t + 256] = 0;
    ((int*)h4)[t + 512] = 0;
    ((int*)h4)[t + 768] = 0;
    __syncthreads();
    int base_i = blockIdx.x * 4096;
#pragma unroll
    for (int j = 0; j < 16; ++j) {
        int i = base_i + j * 256 + t;
        if (i < E) atomicAdd(&h4[w][dst[i] >> 8], 1);
    }
    __syncthreads();
    if (t < NB) {
        int s = h4[0][t] + h4[1][t] + h4[2][t] + h4[3][t];
        if (s) atomicAdd(&bcnt[t], s);
    }
}

// scan bucket counts -> bbase[0..NB], init bcur; zero bufH dummy row. NB<=256.
__global__ void k_bscan(const int* __restrict__ bcnt, int* __restrict__ bbase,
                        int* __restrict__ bcur, int NB,
                        unsigned* __restrict__ hwdummy) {
    __shared__ int s[256];
    int t = threadIdx.x;
    int v = (t < NB) ? bcnt[t] : 0;
    s[t] = v;
    __syncthreads();
    for (int d = 1; d < 256; d <<= 1) {
        int x = (t >= d) ? s[t - d] : 0;
        __syncthreads();
        s[t] += x;
        __syncthreads();
    }
    if (t < NB) {
        int excl = s[t] - v;
        bbase[t] = excl;
        bcur[t]  = excl;
        if (t == NB - 1) bbase[NB] = s[t];   // total == E
    }
    if (t < 64) hwdummy[t] = 0u;             // 256B dummy row
}

// ---------------- pass 1: coarse binning (packed 4B edges) ----------------
// wave-private counts + wave-private cursors over per-wave sub-chunks.

__global__ void k_bin(const int* __restrict__ src, const int* __restrict__ dst,
                      int* __restrict__ bcur, int* __restrict__ bkt,
                      int E, int NB) {
    __shared__ int h4[4][256];
    __shared__ int pw[4][256];
    int t = threadIdx.x;
    int w = t >> 6;
    ((int*)h4)[t]       = 0;
    ((int*)h4)[t + 256] = 0;
    ((int*)h4)[t + 512] = 0;
    ((int*)h4)[t + 768] = 0;
    __syncthreads();

    int base_i = blockIdx.x * 4096;
    int b_[16];
    int v_[16];
#pragma unroll
    for (int j = 0; j < 16; ++j) {
        int i = base_i + j * 256 + t;        // coalesced
        if (i < E) {
            int s = src[i], d = dst[i];
            v_[j] = s | ((d & 255) << 16);   // src(16b) | dlocal(8b)
            int b = d >> 8;
            b_[j] = b;
            atomicAdd(&h4[w][b], 1);
        } else {
            b_[j] = -1;
        }
    }
    __syncthreads();

    if (t < NB) {
        int c0 = h4[0][t], c1 = h4[1][t], c2 = h4[2][t], c3 = h4[3][t];
        int tot = c0 + c1 + c2 + c3;
        int base = tot ? atomicAdd(&bcur[t], tot) : 0;
        pw[0][t] = base;
        pw[1][t] = base + c0;
        pw[2][t] = base + c0 + c1;
        pw[3][t] = base + c0 + c1 + c2;
    }
    __syncthreads();

#pragma unroll
    for (int j = 0; j < 16; ++j) {
        if (b_[j] >= 0) {
            int p = atomicAdd(&pw[w][b_[j]], 1);
            bkt[p] = v_[j];
        }
    }
}

// ---------------- pass 2: per-bucket local CSR build ----------------
// 1024 threads = 4 groups of 256; group-private hist + cursors.

__global__ void k_fill2(const int* __restrict__ bkt, const int* __restrict__ bbase,
                        int* __restrict__ off, float* __restrict__ dinv,
                        int* __restrict__ csr, int N, int E, int NB) {
    __shared__ int h4[4][256];
    __shared__ int loff[256];
    __shared__ int cur4[4][256];
    int b = blockIdx.x, t = threadIdx.x;     // 1024 threads
    int grp = t >> 8;
    ((int*)h4)[t] = 0;
    __syncthreads();

    int e0 = bbase[b], e1 = bbase[b + 1];
    for (int i = e0 + t; i < e1; i += 1024)
        atomicAdd(&h4[grp][(bkt[i] >> 16) & 255], 1);
    __syncthreads();

    int tot = 0;
    if (t < 256) {
        tot = h4[0][t] + h4[1][t] + h4[2][t] + h4[3][t];
        loff[t] = tot;
    }
    __syncthreads();
    for (int d = 1; d < 256; d <<= 1) {
        int x = 0;
        if (t < 256 && t >= d) x = loff[t - d];
        __syncthreads();
        if (t < 256) loff[t] += x;
        __syncthreads();
    }

    if (t < 256) {
        int n = (b << 8) + t;
        if (n < N) {
            int base = e0 + loff[t] - tot;   // exclusive
            off[n]  = base;
            dinv[n] = rsqrtf((float)(tot + 1));  // +1 self-loop
            cur4[0][t] = base;
            cur4[1][t] = base + h4[0][t];
            cur4[2][t] = base + h4[0][t] + h4[1][t];
            cur4[3][t] = base + h4[0][t] + h4[1][t] + h4[2][t];
        }
    }
    if (b == NB - 1 && t == 0) off[N] = E;
    __syncthreads();

    for (int i = e0 + t; i < e1; i += 1024) {
        int v  = bkt[i];
        int dl = (v >> 16) & 255;
        int p  = atomicAdd(&cur4[grp][dl], 1);   // group-private LDS cursor
        csr[p] = v & 0xFFFF;                     // src only
    }
}

// ---------------- MFMA GEMM: hw'[N,128](bf16) = dinv[row]*(in @ W) ----------
// 256 threads = 4 waves; wave = 16 rows x 128 cols; 2 row-tiles per block
// (W LDS-staged once). Operand-swapped MFMA: D=(in@W)^T -> lane owns one
// output row; 8 packed uint2 stores/thread.

template<bool BF16IN>
__global__ __launch_bounds__(256) void k_gemm(
        const void* __restrict__ in_, const float* __restrict__ W,
        const float* __restrict__ dinv, unsigned* __restrict__ outbf, int N) {
    __shared__ unsigned short wbf[128 * 136];       // [col][k], pitch 136

    int t = threadIdx.x;
    int w  = t >> 6;
    int l  = t & 63;
    int lo = l & 15;
    int hi = l >> 4;

    // ---- stage W: coalesced f32 reads, bf16 LDS writes (once per block) ----
#pragma unroll
    for (int i = 0; i < 16; ++i) {
        int idx = (i * 256 + t) * 4;         // 4 consecutive cols, same k
        float4 wv = *reinterpret_cast<const float4*>(W + idx);
        int k = idx >> 7, c = idx & 127;
        wbf[(c    ) * 136 + k] = (unsigned short)f2bf_rne(wv.x);
        wbf[(c + 1) * 136 + k] = (unsigned short)f2bf_rne(wv.y);
        wbf[(c + 2) * 136 + k] = (unsigned short)f2bf_rne(wv.z);
        wbf[(c + 3) * 136 + k] = (unsigned short)f2bf_rne(wv.w);
    }
    __syncthreads();

    unsigned short* outS = (unsigned short*)outbf;

#pragma unroll
    for (int tt = 0; tt < 2; ++tt) {
        int rbase = (blockIdx.x * 2 + tt) * 64 + w * 16;
        if (rbase >= N) continue;            // no barriers below: safe
        int row  = rbase + lo;
        int rowc = (row < N) ? row : (N - 1);

        // in-frag ("B" of swapped mfma): lane l <- in[rbase+(l&15)][(l>>4)*8+j]
        short8 a[4];
        if constexpr (BF16IN) {
            const uint4* pu = (const uint4*)in_;
#pragma unroll
            for (int ks = 0; ks < 4; ++ks)
                a[ks] = __builtin_bit_cast(short8, pu[(size_t)rowc * 16 + ks * 4 + hi]);
        } else {
            const float4* pf = (const float4*)in_;
#pragma unroll
            for (int ks = 0; ks < 4; ++ks) {
                float4 fA = pf[(size_t)rowc * 32 + ks * 8 + hi * 2];
                float4 fB = pf[(size_t)rowc * 32 + ks * 8 + hi * 2 + 1];
                short8 s;
                s[0] = (short)f2bf_rne(fA.x); s[1] = (short)f2bf_rne(fA.y);
                s[2] = (short)f2bf_rne(fA.z); s[3] = (short)f2bf_rne(fA.w);
                s[4] = (short)f2bf_rne(fB.x); s[5] = (short)f2bf_rne(fB.y);
                s[6] = (short)f2bf_rne(fB.z); s[7] = (short)f2bf_rne(fB.w);
                a[ks] = s;
            }
        }

        f32x4v acc[8];
#pragma unroll
        for (int i = 0; i < 8; ++i) acc[i] = (f32x4v){0.f, 0.f, 0.f, 0.f};

        // W-frag ("A" of swapped mfma): lane l <- wbf[tile + (l&15)][...]
#pragma unroll
        for (int cp = 0; cp < 2; ++cp) {
            short8 b[4][4];                  // [ct][ks]
#pragma unroll
            for (int ct = 0; ct < 4; ++ct) {
                int col = cp * 64 + ct * 16 + lo;
#pragma unroll
                for (int ks = 0; ks < 4; ++ks)
                    b[ct][ks] = *reinterpret_cast<const short8*>(
                        &wbf[col * 136 + ks * 32 + hi * 8]);
            }
#pragma unroll
            for (int ks = 0; ks < 4; ++ks)
#pragma unroll
                for (int ct = 0; ct < 4; ++ct)
                    acc[cp * 4 + ct] = __builtin_amdgcn_mfma_f32_16x16x32_bf16(
                        b[ct][ks], a[ks], acc[cp * 4 + ct], 0, 0, 0);
        }

        // epilogue: lane owns row = rbase+lo; acc[i][0..3] = 4 consecutive
        // cols at cp*64+ct*16+hi*4 -> one uint2 (8B) store per acc index
        if (row < N) {
            float d = dinv[row];
#pragma unroll
            for (int i = 0; i < 8; ++i) {
                int colb = (i >> 2) * 64 + (i & 3) * 16 + hi * 4;
                uint2 o = { pack_bf2(acc[i][0] * d, acc[i][1] * d),
                            pack_bf2(acc[i][2] * d, acc[i][3] * d) };
                *reinterpret_cast<uint2*>(&outS[(size_t)row * 128 + colb]) = o;
            }
        }
    }
}

// ---------------- aggregation ----------------
// out[n] = relu(dinv[n]*(sum_e hw'[src_e] + hw'[n]) + b), hw' & out bf16.
// One wave per node; 4 edges per quad (quarter-wave x uint4 = 256B/row),
// 8 quads pipelined -> 8 outstanding gathers/lane.

__global__ void k_aggr(const unsigned* __restrict__ hw, const int* __restrict__ off,
                       const int* __restrict__ csr, const float* __restrict__ dinv,
                       const float* __restrict__ bias, unsigned* __restrict__ out, int N) {
    int wid  = (blockIdx.x * blockDim.x + threadIdx.x) >> 6;
    int lane = threadIdx.x & 63;
    if (wid >= N) return;
    int n  = wid;
    int q  = lane >> 4;                       // quarter 0..3
    int li = lane & 15;                       // lane owns cols 8*li .. 8*li+7

    const uint4* hw4 = reinterpret_cast<const uint4*>(hw);

    float a0 = 0.f, a1 = 0.f, a2 = 0.f, a3 = 0.f;
    float a4 = 0.f, a5 = 0.f, a6 = 0.f, a7 = 0.f;
    if (q == 0) {                             // self term hw'[n] in quarter 0
        uint4 v = hw4[(unsigned)(n << 4) + li];
        a0 = bf_lo(v.x); a1 = bf_hi(v.x);
        a2 = bf_lo(v.y); a3 = bf_hi(v.y);
        a4 = bf_lo(v.z); a5 = bf_hi(v.z);
        a6 = bf_lo(v.w); a7 = bf_hi(v.w);
    }

#define ACC8(v) \
    a0 += bf_lo(v.x); a1 += bf_hi(v.x); \
    a2 += bf_lo(v.y); a3 += bf_hi(v.y); \
    a4 += bf_lo(v.z); a5 += bf_hi(v.z); \
    a6 += bf_lo(v.w); a7 += bf_hi(v.w);

    int e = off[n], e1 = off[n + 1];
    while (e < e1) {
        int rem = e1 - e;
        int cnt = rem < 64 ? rem : 64;
        int s_l = N;                          // invalid -> zero row
        if (lane < cnt) s_l = csr[e + lane];
        int jn = (cnt + 3) >> 2;              // edge quads this batch
        int j = 0;
        for (; j + 8 <= jn; j += 8) {
            int s0 = __shfl(s_l, 4 * j + q);
            int s1 = __shfl(s_l, 4 * j + 4 + q);
            int s2 = __shfl(s_l, 4 * j + 8 + q);
            int s3 = __shfl(s_l, 4 * j + 12 + q);
            int s4 = __shfl(s_l, 4 * j + 16 + q);
            int s5 = __shfl(s_l, 4 * j + 20 + q);
            int s6 = __shfl(s_l, 4 * j + 24 + q);
            int s7 = __shfl(s_l, 4 * j + 28 + q);
            uint4 v0 = hw4[(unsigned)(s0 << 4) + li];
            uint4 v1 = hw4[(unsigned)(s1 << 4) + li];
            uint4 v2 = hw4[(unsigned)(s2 << 4) + li];
            uint4 v3 = hw4[(unsigned)(s3 << 4) + li];
            uint4 v4 = hw4[(unsigned)(s4 << 4) + li];
            uint4 v5 = hw4[(unsigned)(s5 << 4) + li];
            uint4 v6 = hw4[(unsigned)(s6 << 4) + li];
            uint4 v7 = hw4[(unsigned)(s7 << 4) + li];
            ACC8(v0) ACC8(v1) ACC8(v2) ACC8(v3)
            ACC8(v4) ACC8(v5) ACC8(v6) ACC8(v7)
        }
        for (; j + 4 <= jn; j += 4) {
            int s0 = __shfl(s_l, 4 * j + q);
            int s1 = __shfl(s_l, 4 * j + 4 + q);
            int s2 = __shfl(s_l, 4 * j + 8 + q);
            int s3 = __shfl(s_l, 4 * j + 12 + q);
            uint4 v0 = hw4[(unsigned)(s0 << 4) + li];
            uint4 v1 = hw4[(unsigned)(s1 << 4) + li];
            uint4 v2 = hw4[(unsigned)(s2 << 4) + li];
            uint4 v3 = hw4[(unsigned)(s3 << 4) + li];
            ACC8(v0) ACC8(v1) ACC8(v2) ACC8(v3)
        }
        for (; j < jn; ++j) {
            int   s = __shfl(s_l, 4 * j + q); // idx>=cnt lanes hold N -> zeros
            uint4 v = hw4[(unsigned)(s << 4) + li];
            ACC8(v)
        }
        e += cnt;
    }
#undef ACC8

    // combine quarters: q0+=q2, q1+=q3 (partner +32), then q0+=q1 (+16)
    int p1 = (lane + 32) & 63;
    a0 += __shfl(a0, p1); a1 += __shfl(a1, p1);
    a2 += __shfl(a2, p1); a3 += __shfl(a3, p1);
    a4 += __shfl(a4, p1); a5 += __shfl(a5, p1);
    a6 += __shfl(a6, p1); a7 += __shfl(a7, p1);
    int p2 = (lane + 16) & 63;
    a0 += __shfl(a0, p2); a1 += __shfl(a1, p2);
    a2 += __shfl(a2, p2); a3 += __shfl(a3, p2);
    a4 += __shfl(a4, p2); a5 += __shfl(a5, p2);
    a6 += __shfl(a6, p2); a7 += __shfl(a7, p2);

    if (q == 0) {
        float di = dinv[n];
        const float4* b4 = reinterpret_cast<const float4*>(bias);
        float4 bA = b4[2 * li], bB = b4[2 * li + 1];
        a0 = fmaxf(fmaf(a0, di, bA.x), 0.f); a1 = fmaxf(fmaf(a1, di, bA.y), 0.f);
        a2 = fmaxf(fmaf(a2, di, bA.z), 0.f); a3 = fmaxf(fmaf(a3, di, bA.w), 0.f);
        a4 = fmaxf(fmaf(a4, di, bB.x), 0.f); a5 = fmaxf(fmaf(a5, di, bB.y), 0.f);
        a6 = fmaxf(fmaf(a6, di, bB.z), 0.f); a7 = fmaxf(fmaf(a7, di, bB.w), 0.f);
        uint4 r = { pack_bf2(a0, a1), pack_bf2(a2, a3),
                    pack_bf2(a4, a5), pack_bf2(a6, a7) };
        reinterpret_cast<uint4*>(out)[(unsigned)(n << 4) + li] = r;
    }
}

// ---------------- MLP head + L2 normalize, with fused mean-pool ----------------
// One block per graph (128 threads). Node range via binary search in sorted
// batch; pooling reads h (bf16) directly, f32 accumulate; count = range len.

__global__ void k_head(const unsigned* __restrict__ h, const int* __restrict__ batch,
                       int N,
                       const float* __restrict__ pW1, const float* __restrict__ pb1,
                       const float* __restrict__ pW2, const float* __restrict__ pb2,
                       float* __restrict__ out) {
    __shared__ float hg[128];
    __shared__ float z1[128];
    __shared__ float red[128];
    int g = blockIdx.x, t = threadIdx.x;   // 128 threads

    // [start, end) = node range of graph g (batch sorted ascending)
    int lo = 0, hi = N;
    while (lo < hi) { int m = (lo + hi) >> 1; if (batch[m] < g) lo = m + 1; else hi = m; }
    int start = lo;
    hi = N;
    while (lo < hi) { int m = (lo + hi) >> 1; if (batch[m] < g + 1) lo = m + 1; else hi = m; }
    int end = lo;

    // pool feature t over [start, end)
    int  ui   = t >> 1;                    // uint index within row (2 bf16/uint)
    bool hiH  = t & 1;
    float acc = 0.f;
    for (int n = start; n < end; ++n) {
        unsigned v = h[(size_t)n * 64 + ui];
        acc += hiH ? bf_hi(v) : bf_lo(v);
    }
    float c = fmaxf((float)(end - start), 1.0f);
    hg[t] = acc / c;
    __syncthreads();

    float a = pb1[t];
#pragma unroll 8
    for (int k = 0; k < 128; ++k) a = fmaf(hg[k], pW1[k * 128 + t], a);
    z1[t] = fmaxf(a, 0.f);
    __syncthreads();

    float z = pb2[t];
#pragma unroll 8
    for (int k = 0; k < 128; ++k) z = fmaf(z1[k], pW2[k * 128 + t], z);

    red[t] = z * z;
    __syncthreads();
    for (int d = 64; d > 0; d >>= 1) {
        if (t < d) red[t] += red[t + d];
        __syncthreads();
    }
    float nrm = fmaxf(sqrtf(red[0]), 1e-12f);
    out[g * 128 + t] = z / nrm;
}

// ---------------------------------------------------------------------------

extern "C" void kernel_launch(void* const* d_in, const int* in_sizes, int n_in,
                              void* d_out, int out_size, void* d_ws, size_t ws_size,
                              hipStream_t stream) {
    const float* x    = (const float*)d_in[0];
    const int*   eidx = (const int*)  d_in[1];
    const int*   batch= (const int*)  d_in[2];
    const float* W1   = (const float*)d_in[4];
    const float* b1   = (const float*)d_in[5];
    const float* W2   = (const float*)d_in[6];
    const float* b2   = (const float*)d_in[7];
    const float* pW1  = (const float*)d_in[8];
    const float* pb1  = (const float*)d_in[9];
    const float* pW2  = (const float*)d_in[10];
    const float* pb2  = (const float*)d_in[11];
    float* out = (float*)d_out;

    const int N  = in_sizes[0] / 128;
    const int E  = in_sizes[1] / 2;
    const int NG = out_size / 128;
    const int NB = (N + 255) >> 8;    // buckets of 256 nodes; NB<=256 (N<65536)

    const int* src = eidx;      // edge_index[0]
    const int* dst = eidx + E;  // edge_index[1]

    // workspace carve-up (256B aligned)
    char* p = (char*)d_ws;
    auto alloc = [&](size_t bytes) -> void* {
        void* r = (void*)p;
        p += (bytes + 255) & ~(size_t)255;
        return r;
    };
    int*      bcnt     = (int*)     alloc((size_t)NB * 4);
    int*      bbase    = (int*)     alloc((size_t)(NB + 1) * 4);
    int*      bcur     = (int*)     alloc((size_t)NB * 4);
    int*      off      = (int*)     alloc((size_t)(N + 1) * 4);
    float*    dinv     = (float*)   alloc((size_t)N * 4);
    int*      bkt      = (int*)     alloc((size_t)E * 4);        // packed edges
    int*      csr      = (int*)     alloc((size_t)E * 4);        // src only
    unsigned* bufH     = (unsigned*)alloc((size_t)(N + 1) * 64 * 4); // bf16 hw' (+zero row)
    unsigned* bufB     = (unsigned*)alloc((size_t)N * 64 * 4);       // bf16 h
    (void)ws_size;

    const int tB = (E + 4095) / 4096;   // 4096-edge tiles

    hipMemsetAsync(bcnt, 0, (size_t)NB * 4, stream);   // only pre-bincount zero

    // CSR build: count -> scan(+dummy-row zero) -> bin -> per-bucket fill
    k_bincount<<<tB, 256, 0, stream>>>(dst, bcnt, E, NB);
    k_bscan   <<<1, 256, 0, stream>>>(bcnt, bbase, bcur, NB,
                                      bufH + (size_t)N * 64);
    k_bin     <<<tB, 256, 0, stream>>>(src, dst, bcur, bkt, E, NB);
    k_fill2   <<<NB, 1024, 0, stream>>>(bkt, bbase, off, dinv, csr, N, E, NB);

    const int nrt = (N + 63) / 64;              // 64-row tiles
    const int gB  = (nrt + 1) / 2;              // 2 tiles per block
    const int aB  = (N + 3) / 4;                // 4 waves (nodes) per block

    // layer 1: hw' = bf16(dinv*(x @ W1)) ; h1 = bf16(relu(dinv*aggr + b1))
    k_gemm<false><<<gB, 256, 0, stream>>>((const void*)x, W1, dinv, bufH, N);
    k_aggr<<<aB, 256, 0, stream>>>(bufH, off, csr, dinv, b1, bufB, N);
    // layer 2
    k_gemm<true><<<gB, 256, 0, stream>>>((const void*)bufB, W2, dinv, bufH, N);
    k_aggr<<<aB, 256, 0, stream>>>(bufH, off, csr, dinv, b2, bufB, N);

    // fused mean-pool + MLP head + L2 normalize
    k_head<<<NG, 128, 0, stream>>>(bufB, batch, N, pW1, pb1, pW2, pb2, out);
}

// Round 16
// 220.892 us; speedup vs baseline: 1.8587x; 1.8587x over previous
//
#include <hip/hip_runtime.h>
#include <cstdint>
#include <cstddef>

// ---------------------------------------------------------------------------
// SimpleGNN: 2x GCNConv(128->128) + ReLU, global mean pool (64 graphs),
// MLP head 128->128->128 + ReLU, L2 row-normalize.
//
// R16 = R15's CSR improvements (wave-private histograms, ~28us saved) with
// the k_pool fusion REVERTED (R15's 64-block fused head ran at 1.3% occupancy
// = 226us). k_pool (N/32 waves, sorted-batch range accumulation) + separate
// k_head restored from R14; pooled/cnt zeroing absorbed into k_bscan.
// ---------------------------------------------------------------------------

using short8 = __attribute__((ext_vector_type(8))) short;   // 8 bf16 (4 VGPRs)
using f32x4v = __attribute__((ext_vector_type(4))) float;   // 4 fp32

// ---------------- bf16 helpers ----------------

static __device__ __forceinline__ unsigned f2bf_rne(float f) {
    unsigned u = __float_as_uint(f);
    return (u + 0x7FFFu + ((u >> 16) & 1u)) >> 16;   // round-nearest-even
}
static __device__ __forceinline__ unsigned pack_bf2(float lo, float hi) {
    return f2bf_rne(lo) | (f2bf_rne(hi) << 16);
}
static __device__ __forceinline__ float bf_lo(unsigned v) {
    return __uint_as_float(v << 16);
}
static __device__ __forceinline__ float bf_hi(unsigned v) {
    return __uint_as_float(v & 0xFFFF0000u);
}

// ---------------- pass 0: bucket counts (bucket = 256 consecutive dst) ----
// wave-private histograms -> 4x less LDS-atomic contention

__global__ void k_bincount(const int* __restrict__ dst, int* __restrict__ bcnt,
                           int E, int NB) {
    __shared__ int h4[4][256];
    int t = threadIdx.x;
    int w = t >> 6;
    ((int*)h4)[t]       = 0;
    ((int*)h4)[t + 256] = 0;
    ((int*)h4)[t + 512] = 0;
    ((int*)h4)[t + 768] = 0;
    __syncthreads();
    int base_i = blockIdx.x * 4096;
#pragma unroll
    for (int j = 0; j < 16; ++j) {
        int i = base_i + j * 256 + t;
        if (i < E) atomicAdd(&h4[w][dst[i] >> 8], 1);
    }
    __syncthreads();
    if (t < NB) {
        int s = h4[0][t] + h4[1][t] + h4[2][t] + h4[3][t];
        if (s) atomicAdd(&bcnt[t], s);
    }
}

// scan bucket counts -> bbase[0..NB], init bcur; zero pooled/cnt and the
// bufH dummy row (absorbed memsets). NB <= 256.
__global__ void k_bscan(const int* __restrict__ bcnt, int* __restrict__ bbase,
                        int* __restrict__ bcur, int NB,
                        float* __restrict__ pooled, int* __restrict__ cnt,
                        unsigned* __restrict__ hwdummy, int NG) {
    __shared__ int s[256];
    int t = threadIdx.x;
    int v = (t < NB) ? bcnt[t] : 0;
    s[t] = v;
    __syncthreads();
    for (int d = 1; d < 256; d <<= 1) {
        int x = (t >= d) ? s[t - d] : 0;
        __syncthreads();
        s[t] += x;
        __syncthreads();
    }
    if (t < NB) {
        int excl = s[t] - v;
        bbase[t] = excl;
        bcur[t]  = excl;
        if (t == NB - 1) bbase[NB] = s[t];   // total == E
    }
    // absorbed zero-inits (used only by later kernels)
    float4 z4 = {0.f, 0.f, 0.f, 0.f};
    int n4 = NG * 32;                        // pooled = NG*128 floats
    for (int i = t; i < n4; i += 256)
        reinterpret_cast<float4*>(pooled)[i] = z4;
    if (t < NG) cnt[t] = 0;
    if (t < 64) hwdummy[t] = 0u;             // 256B dummy row
}

// ---------------- pass 1: coarse binning (packed 4B edges) ----------------
// wave-private counts + wave-private cursors over per-wave sub-chunks.

__global__ void k_bin(const int* __restrict__ src, const int* __restrict__ dst,
                      int* __restrict__ bcur, int* __restrict__ bkt,
                      int E, int NB) {
    __shared__ int h4[4][256];
    __shared__ int pw[4][256];
    int t = threadIdx.x;
    int w = t >> 6;
    ((int*)h4)[t]       = 0;
    ((int*)h4)[t + 256] = 0;
    ((int*)h4)[t + 512] = 0;
    ((int*)h4)[t + 768] = 0;
    __syncthreads();

    int base_i = blockIdx.x * 4096;
    int b_[16];
    int v_[16];
#pragma unroll
    for (int j = 0; j < 16; ++j) {
        int i = base_i + j * 256 + t;        // coalesced
        if (i < E) {
            int s = src[i], d = dst[i];
            v_[j] = s | ((d & 255) << 16);   // src(16b) | dlocal(8b)
            int b = d >> 8;
            b_[j] = b;
            atomicAdd(&h4[w][b], 1);
        } else {
            b_[j] = -1;
        }
    }
    __syncthreads();

    if (t < NB) {
        int c0 = h4[0][t], c1 = h4[1][t], c2 = h4[2][t], c3 = h4[3][t];
        int tot = c0 + c1 + c2 + c3;
        int base = tot ? atomicAdd(&bcur[t], tot) : 0;
        pw[0][t] = base;
        pw[1][t] = base + c0;
        pw[2][t] = base + c0 + c1;
        pw[3][t] = base + c0 + c1 + c2;
    }
    __syncthreads();

#pragma unroll
    for (int j = 0; j < 16; ++j) {
        if (b_[j] >= 0) {
            int p = atomicAdd(&pw[w][b_[j]], 1);
            bkt[p] = v_[j];
        }
    }
}

// ---------------- pass 2: per-bucket local CSR build ----------------
// 1024 threads = 4 groups of 256; group-private hist + cursors.

__global__ void k_fill2(const int* __restrict__ bkt, const int* __restrict__ bbase,
                        int* __restrict__ off, float* __restrict__ dinv,
                        int* __restrict__ csr, int N, int E, int NB) {
    __shared__ int h4[4][256];
    __shared__ int loff[256];
    __shared__ int cur4[4][256];
    int b = blockIdx.x, t = threadIdx.x;     // 1024 threads
    int grp = t >> 8;
    ((int*)h4)[t] = 0;
    __syncthreads();

    int e0 = bbase[b], e1 = bbase[b + 1];
    for (int i = e0 + t; i < e1; i += 1024)
        atomicAdd(&h4[grp][(bkt[i] >> 16) & 255], 1);
    __syncthreads();

    int tot = 0;
    if (t < 256) {
        tot = h4[0][t] + h4[1][t] + h4[2][t] + h4[3][t];
        loff[t] = tot;
    }
    __syncthreads();
    for (int d = 1; d < 256; d <<= 1) {
        int x = 0;
        if (t < 256 && t >= d) x = loff[t - d];
        __syncthreads();
        if (t < 256) loff[t] += x;
        __syncthreads();
    }

    if (t < 256) {
        int n = (b << 8) + t;
        if (n < N) {
            int base = e0 + loff[t] - tot;   // exclusive
            off[n]  = base;
            dinv[n] = rsqrtf((float)(tot + 1));  // +1 self-loop
            cur4[0][t] = base;
            cur4[1][t] = base + h4[0][t];
            cur4[2][t] = base + h4[0][t] + h4[1][t];
            cur4[3][t] = base + h4[0][t] + h4[1][t] + h4[2][t];
        }
    }
    if (b == NB - 1 && t == 0) off[N] = E;
    __syncthreads();

    for (int i = e0 + t; i < e1; i += 1024) {
        int v  = bkt[i];
        int dl = (v >> 16) & 255;
        int p  = atomicAdd(&cur4[grp][dl], 1);   // group-private LDS cursor
        csr[p] = v & 0xFFFF;                     // src only
    }
}

// ---------------- MFMA GEMM: hw'[N,128](bf16) = dinv[row]*(in @ W) ----------
// 256 threads = 4 waves; wave = 16 rows x 128 cols; 2 row-tiles per block
// (W LDS-staged once). Operand-swapped MFMA: D=(in@W)^T -> lane owns one
// output row; 8 packed uint2 stores/thread.

template<bool BF16IN>
__global__ __launch_bounds__(256) void k_gemm(
        const void* __restrict__ in_, const float* __restrict__ W,
        const float* __restrict__ dinv, unsigned* __restrict__ outbf, int N) {
    __shared__ unsigned short wbf[128 * 136];       // [col][k], pitch 136

    int t = threadIdx.x;
    int w  = t >> 6;
    int l  = t & 63;
    int lo = l & 15;
    int hi = l >> 4;

    // ---- stage W: coalesced f32 reads, bf16 LDS writes (once per block) ----
#pragma unroll
    for (int i = 0; i < 16; ++i) {
        int idx = (i * 256 + t) * 4;         // 4 consecutive cols, same k
        float4 wv = *reinterpret_cast<const float4*>(W + idx);
        int k = idx >> 7, c = idx & 127;
        wbf[(c    ) * 136 + k] = (unsigned short)f2bf_rne(wv.x);
        wbf[(c + 1) * 136 + k] = (unsigned short)f2bf_rne(wv.y);
        wbf[(c + 2) * 136 + k] = (unsigned short)f2bf_rne(wv.z);
        wbf[(c + 3) * 136 + k] = (unsigned short)f2bf_rne(wv.w);
    }
    __syncthreads();

    unsigned short* outS = (unsigned short*)outbf;

#pragma unroll
    for (int tt = 0; tt < 2; ++tt) {
        int rbase = (blockIdx.x * 2 + tt) * 64 + w * 16;
        if (rbase >= N) continue;            // no barriers below: safe
        int row  = rbase + lo;
        int rowc = (row < N) ? row : (N - 1);

        // in-frag ("B" of swapped mfma): lane l <- in[rbase+(l&15)][(l>>4)*8+j]
        short8 a[4];
        if constexpr (BF16IN) {
            const uint4* pu = (const uint4*)in_;
#pragma unroll
            for (int ks = 0; ks < 4; ++ks)
                a[ks] = __builtin_bit_cast(short8, pu[(size_t)rowc * 16 + ks * 4 + hi]);
        } else {
            const float4* pf = (const float4*)in_;
#pragma unroll
            for (int ks = 0; ks < 4; ++ks) {
                float4 fA = pf[(size_t)rowc * 32 + ks * 8 + hi * 2];
                float4 fB = pf[(size_t)rowc * 32 + ks * 8 + hi * 2 + 1];
                short8 s;
                s[0] = (short)f2bf_rne(fA.x); s[1] = (short)f2bf_rne(fA.y);
                s[2] = (short)f2bf_rne(fA.z); s[3] = (short)f2bf_rne(fA.w);
                s[4] = (short)f2bf_rne(fB.x); s[5] = (short)f2bf_rne(fB.y);
                s[6] = (short)f2bf_rne(fB.z); s[7] = (short)f2bf_rne(fB.w);
                a[ks] = s;
            }
        }

        f32x4v acc[8];
#pragma unroll
        for (int i = 0; i < 8; ++i) acc[i] = (f32x4v){0.f, 0.f, 0.f, 0.f};

        // W-frag ("A" of swapped mfma): lane l <- wbf[tile + (l&15)][...]
#pragma unroll
        for (int cp = 0; cp < 2; ++cp) {
            short8 b[4][4];                  // [ct][ks]
#pragma unroll
            for (int ct = 0; ct < 4; ++ct) {
                int col = cp * 64 + ct * 16 + lo;
#pragma unroll
                for (int ks = 0; ks < 4; ++ks)
                    b[ct][ks] = *reinterpret_cast<const short8*>(
                        &wbf[col * 136 + ks * 32 + hi * 8]);
            }
#pragma unroll
            for (int ks = 0; ks < 4; ++ks)
#pragma unroll
                for (int ct = 0; ct < 4; ++ct)
                    acc[cp * 4 + ct] = __builtin_amdgcn_mfma_f32_16x16x32_bf16(
                        b[ct][ks], a[ks], acc[cp * 4 + ct], 0, 0, 0);
        }

        // epilogue: lane owns row = rbase+lo; acc[i][0..3] = 4 consecutive
        // cols at cp*64+ct*16+hi*4 -> one uint2 (8B) store per acc index
        if (row < N) {
            float d = dinv[row];
#pragma unroll
            for (int i = 0; i < 8; ++i) {
                int colb = (i >> 2) * 64 + (i & 3) * 16 + hi * 4;
                uint2 o = { pack_bf2(acc[i][0] * d, acc[i][1] * d),
                            pack_bf2(acc[i][2] * d, acc[i][3] * d) };
                *reinterpret_cast<uint2*>(&outS[(size_t)row * 128 + colb]) = o;
            }
        }
    }
}

// ---------------- aggregation ----------------
// out[n] = relu(dinv[n]*(sum_e hw'[src_e] + hw'[n]) + b), hw' & out bf16.
// One wave per node; 4 edges per quad (quarter-wave x uint4 = 256B/row),
// 8 quads pipelined -> 8 outstanding gathers/lane.

__global__ void k_aggr(const unsigned* __restrict__ hw, const int* __restrict__ off,
                       const int* __restrict__ csr, const float* __restrict__ dinv,
                       const float* __restrict__ bias, unsigned* __restrict__ out, int N) {
    int wid  = (blockIdx.x * blockDim.x + threadIdx.x) >> 6;
    int lane = threadIdx.x & 63;
    if (wid >= N) return;
    int n  = wid;
    int q  = lane >> 4;                       // quarter 0..3
    int li = lane & 15;                       // lane owns cols 8*li .. 8*li+7

    const uint4* hw4 = reinterpret_cast<const uint4*>(hw);

    float a0 = 0.f, a1 = 0.f, a2 = 0.f, a3 = 0.f;
    float a4 = 0.f, a5 = 0.f, a6 = 0.f, a7 = 0.f;
    if (q == 0) {                             // self term hw'[n] in quarter 0
        uint4 v = hw4[(unsigned)(n << 4) + li];
        a0 = bf_lo(v.x); a1 = bf_hi(v.x);
        a2 = bf_lo(v.y); a3 = bf_hi(v.y);
        a4 = bf_lo(v.z); a5 = bf_hi(v.z);
        a6 = bf_lo(v.w); a7 = bf_hi(v.w);
    }

#define ACC8(v) \
    a0 += bf_lo(v.x); a1 += bf_hi(v.x); \
    a2 += bf_lo(v.y); a3 += bf_hi(v.y); \
    a4 += bf_lo(v.z); a5 += bf_hi(v.z); \
    a6 += bf_lo(v.w); a7 += bf_hi(v.w);

    int e = off[n], e1 = off[n + 1];
    while (e < e1) {
        int rem = e1 - e;
        int cnt = rem < 64 ? rem : 64;
        int s_l = N;                          // invalid -> zero row
        if (lane < cnt) s_l = csr[e + lane];
        int jn = (cnt + 3) >> 2;              // edge quads this batch
        int j = 0;
        for (; j + 8 <= jn; j += 8) {
            int s0 = __shfl(s_l, 4 * j + q);
            int s1 = __shfl(s_l, 4 * j + 4 + q);
            int s2 = __shfl(s_l, 4 * j + 8 + q);
            int s3 = __shfl(s_l, 4 * j + 12 + q);
            int s4 = __shfl(s_l, 4 * j + 16 + q);
            int s5 = __shfl(s_l, 4 * j + 20 + q);
            int s6 = __shfl(s_l, 4 * j + 24 + q);
            int s7 = __shfl(s_l, 4 * j + 28 + q);
            uint4 v0 = hw4[(unsigned)(s0 << 4) + li];
            uint4 v1 = hw4[(unsigned)(s1 << 4) + li];
            uint4 v2 = hw4[(unsigned)(s2 << 4) + li];
            uint4 v3 = hw4[(unsigned)(s3 << 4) + li];
            uint4 v4 = hw4[(unsigned)(s4 << 4) + li];
            uint4 v5 = hw4[(unsigned)(s5 << 4) + li];
            uint4 v6 = hw4[(unsigned)(s6 << 4) + li];
            uint4 v7 = hw4[(unsigned)(s7 << 4) + li];
            ACC8(v0) ACC8(v1) ACC8(v2) ACC8(v3)
            ACC8(v4) ACC8(v5) ACC8(v6) ACC8(v7)
        }
        for (; j + 4 <= jn; j += 4) {
            int s0 = __shfl(s_l, 4 * j + q);
            int s1 = __shfl(s_l, 4 * j + 4 + q);
            int s2 = __shfl(s_l, 4 * j + 8 + q);
            int s3 = __shfl(s_l, 4 * j + 12 + q);
            uint4 v0 = hw4[(unsigned)(s0 << 4) + li];
            uint4 v1 = hw4[(unsigned)(s1 << 4) + li];
            uint4 v2 = hw4[(unsigned)(s2 << 4) + li];
            uint4 v3 = hw4[(unsigned)(s3 << 4) + li];
            ACC8(v0) ACC8(v1) ACC8(v2) ACC8(v3)
        }
        for (; j < jn; ++j) {
            int   s = __shfl(s_l, 4 * j + q); // idx>=cnt lanes hold N -> zeros
            uint4 v = hw4[(unsigned)(s << 4) + li];
            ACC8(v)
        }
        e += cnt;
    }
#undef ACC8

    // combine quarters: q0+=q2, q1+=q3 (partner +32), then q0+=q1 (+16)
    int p1 = (lane + 32) & 63;
    a0 += __shfl(a0, p1); a1 += __shfl(a1, p1);
    a2 += __shfl(a2, p1); a3 += __shfl(a3, p1);
    a4 += __shfl(a4, p1); a5 += __shfl(a5, p1);
    a6 += __shfl(a6, p1); a7 += __shfl(a7, p1);
    int p2 = (lane + 16) & 63;
    a0 += __shfl(a0, p2); a1 += __shfl(a1, p2);
    a2 += __shfl(a2, p2); a3 += __shfl(a3, p2);
    a4 += __shfl(a4, p2); a5 += __shfl(a5, p2);
    a6 += __shfl(a6, p2); a7 += __shfl(a7, p2);

    if (q == 0) {
        float di = dinv[n];
        const float4* b4 = reinterpret_cast<const float4*>(bias);
        float4 bA = b4[2 * li], bB = b4[2 * li + 1];
        a0 = fmaxf(fmaf(a0, di, bA.x), 0.f); a1 = fmaxf(fmaf(a1, di, bA.y), 0.f);
        a2 = fmaxf(fmaf(a2, di, bA.z), 0.f); a3 = fmaxf(fmaf(a3, di, bA.w), 0.f);
        a4 = fmaxf(fmaf(a4, di, bB.x), 0.f); a5 = fmaxf(fmaf(a5, di, bB.y), 0.f);
        a6 = fmaxf(fmaf(a6, di, bB.z), 0.f); a7 = fmaxf(fmaf(a7, di, bB.w), 0.f);
        uint4 r = { pack_bf2(a0, a1), pack_bf2(a2, a3),
                    pack_bf2(a4, a5), pack_bf2(a6, a7) };
        reinterpret_cast<uint4*>(out)[(unsigned)(n << 4) + li] = r;
    }
}

// ---------------- global mean pool (batch is sorted, h in bf16) ----------------
// wave processes a contiguous node range; flush atomics only on graph change.

__global__ void k_pool(const unsigned* __restrict__ h, const int* __restrict__ batch,
                       float* __restrict__ pooled, int* __restrict__ cnt,
                       int N, int npw) {
    int wid  = (blockIdx.x * blockDim.x + threadIdx.x) >> 6;
    int lane = threadIdx.x & 63;
    int n0 = wid * npw;
    if (n0 >= N) return;
    int n1 = n0 + npw; if (n1 > N) n1 = N;

    float ax = 0.f, ay = 0.f;
    int g = batch[n0];
    int c = 0;
    for (int n = n0; n < n1; ++n) {
        int gn = batch[n];
        if (gn != g) {
            atomicAdd(&pooled[g * 128 + 2 * lane],     ax);
            atomicAdd(&pooled[g * 128 + 2 * lane + 1], ay);
            if (lane == 0) atomicAdd(&cnt[g], c);
            ax = 0.f; ay = 0.f; c = 0; g = gn;
        }
        unsigned v = h[(size_t)n * 64 + lane];
        ax += bf_lo(v); ay += bf_hi(v); ++c;
    }
    atomicAdd(&pooled[g * 128 + 2 * lane],     ax);
    atomicAdd(&pooled[g * 128 + 2 * lane + 1], ay);
    if (lane == 0) atomicAdd(&cnt[g], c);
}

// ---------------- MLP head + L2 normalize (tiny: 64 x 128) ----------------

__global__ void k_head(const float* __restrict__ pooled, const int* __restrict__ cnt,
                       const float* __restrict__ pW1, const float* __restrict__ pb1,
                       const float* __restrict__ pW2, const float* __restrict__ pb2,
                       float* __restrict__ out) {
    __shared__ float hg[128];
    __shared__ float z1[128];
    __shared__ float red[128];
    int g = blockIdx.x, t = threadIdx.x;   // 128 threads

    float c = fmaxf((float)cnt[g], 1.0f);
    hg[t] = pooled[g * 128 + t] / c;
    __syncthreads();

    float a = pb1[t];
#pragma unroll 8
    for (int k = 0; k < 128; ++k) a = fmaf(hg[k], pW1[k * 128 + t], a);
    z1[t] = fmaxf(a, 0.f);
    __syncthreads();

    float z = pb2[t];
#pragma unroll 8
    for (int k = 0; k < 128; ++k) z = fmaf(z1[k], pW2[k * 128 + t], z);

    red[t] = z * z;
    __syncthreads();
    for (int d = 64; d > 0; d >>= 1) {
        if (t < d) red[t] += red[t + d];
        __syncthreads();
    }
    float nrm = fmaxf(sqrtf(red[0]), 1e-12f);
    out[g * 128 + t] = z / nrm;
}

// ---------------------------------------------------------------------------

extern "C" void kernel_launch(void* const* d_in, const int* in_sizes, int n_in,
                              void* d_out, int out_size, void* d_ws, size_t ws_size,
                              hipStream_t stream) {
    const float* x    = (const float*)d_in[0];
    const int*   eidx = (const int*)  d_in[1];
    const int*   batch= (const int*)  d_in[2];
    const float* W1   = (const float*)d_in[4];
    const float* b1   = (const float*)d_in[5];
    const float* W2   = (const float*)d_in[6];
    const float* b2   = (const float*)d_in[7];
    const float* pW1  = (const float*)d_in[8];
    const float* pb1  = (const float*)d_in[9];
    const float* pW2  = (const float*)d_in[10];
    const float* pb2  = (const float*)d_in[11];
    float* out = (float*)d_out;

    const int N  = in_sizes[0] / 128;
    const int E  = in_sizes[1] / 2;
    const int NG = out_size / 128;
    const int NB = (N + 255) >> 8;    // buckets of 256 nodes; NB<=256 (N<65536)

    const int* src = eidx;      // edge_index[0]
    const int* dst = eidx + E;  // edge_index[1]

    // workspace carve-up (256B aligned)
    char* p = (char*)d_ws;
    auto alloc = [&](size_t bytes) -> void* {
        void* r = (void*)p;
        p += (bytes + 255) & ~(size_t)255;
        return r;
    };
    int*      bcnt     = (int*)     alloc((size_t)NB * 4);
    int*      cnt      = (int*)     alloc((size_t)NG * 4);
    float*    pooled   = (float*)   alloc((size_t)NG * 128 * 4);
    int*      bbase    = (int*)     alloc((size_t)(NB + 1) * 4);
    int*      bcur     = (int*)     alloc((size_t)NB * 4);
    int*      off      = (int*)     alloc((size_t)(N + 1) * 4);
    float*    dinv     = (float*)   alloc((size_t)N * 4);
    int*      bkt      = (int*)     alloc((size_t)E * 4);        // packed edges
    int*      csr      = (int*)     alloc((size_t)E * 4);        // src only
    unsigned* bufH     = (unsigned*)alloc((size_t)(N + 1) * 64 * 4); // bf16 hw' (+zero row)
    unsigned* bufB     = (unsigned*)alloc((size_t)N * 64 * 4);       // bf16 h
    (void)ws_size;

    const int tB = (E + 4095) / 4096;   // 4096-edge tiles

    hipMemsetAsync(bcnt, 0, (size_t)NB * 4, stream);   // only pre-bincount zero

    // CSR build: count -> scan(+absorbed zeroing) -> bin -> per-bucket fill
    k_bincount<<<tB, 256, 0, stream>>>(dst, bcnt, E, NB);
    k_bscan   <<<1, 256, 0, stream>>>(bcnt, bbase, bcur, NB,
                                      pooled, cnt, bufH + (size_t)N * 64, NG);
    k_bin     <<<tB, 256, 0, stream>>>(src, dst, bcur, bkt, E, NB);
    k_fill2   <<<NB, 1024, 0, stream>>>(bkt, bbase, off, dinv, csr, N, E, NB);

    const int nrt = (N + 63) / 64;              // 64-row tiles
    const int gB  = (nrt + 1) / 2;              // 2 tiles per block
    const int aB  = (N + 3) / 4;                // 4 waves (nodes) per block

    // layer 1: hw' = bf16(dinv*(x @ W1)) ; h1 = bf16(relu(dinv*aggr + b1))
    k_gemm<false><<<gB, 256, 0, stream>>>((const void*)x, W1, dinv, bufH, N);
    k_aggr<<<aB, 256, 0, stream>>>(bufH, off, csr, dinv, b1, bufB, N);
    // layer 2
    k_gemm<true><<<gB, 256, 0, stream>>>((const void*)bufB, W2, dinv, bufH, N);
    k_aggr<<<aB, 256, 0, stream>>>(bufH, off, csr, dinv, b2, bufB, N);

    // mean pool (N/32 waves, contiguous ranges, flush on graph change)
    const int NPW = 32;  // nodes per wave
    const int waves = (N + NPW - 1) / NPW;
    const int pB = (waves * 64 + 255) / 256;
    k_pool<<<pB, 256, 0, stream>>>(bufB, batch, pooled, cnt, N, NPW);

    // head
    k_head<<<NG, 128, 0, stream>>>(pooled, cnt, pW1, pb1, pW2, pb2, out);
}